// Round 7
// baseline (249.991 us; speedup 1.0000x reference)
//
#include <hip/hip_runtime.h>

// SPGG Q-learning step on a 2048x2048 torus — SINGLE fused kernel, v6b
// ("regflow": horizontal 4-cell threads, NO LDS at all).
// (Round-6 resubmit: previous bench died on container infra, kernel never ran.)
//
// v6 failed ONLY on output 1 (type_t1, absmax=1.0): a stray
// "placate init warning" line inside the unrolled pack loop re-zeroed
// t14.x on iterations k=1..3, clobbering cell 0's selection. Q_new passed,
// so all stencil/profit/index math is correct. v6b removes the clobber
// (constant-indexed sel array, packed once). No other changes.
//
// Structure (from v6): each thread owns 4 HORIZONTAL cells (i, j0..j0+3):
//   - per-cell I/O fully vectorized: ldir/lp/tmin one int4/float4 each,
//     own Q = 4 contiguous float4, all stores contiguous float4;
//   - the 7-row tt window (46 cells) loads into REGISTERS via 17 aligned
//     dword/x2/x4 loads; row base addrs are SCALAR (one row per block);
//   - all 28 b-values and all 14 candidate profits computed in registers;
//     neighbor choice is a ?:-chain over constant-indexed regs;
//   - ldir issued FIRST (in-order vmcnt: its wait doesn't drain tt loads);
//     gathers issue immediately after and fly under b/profit compute;
//   - zero LDS / zero fences: the wave is one pure dataflow block;
//   - tt row reuse (7x) served by L1/L2 (tt = 16 MB, L2-resident).
//
// Numerics: identical per-cell op sequence as the passing v1-v5 (int-exact
// coop sums; __f*_rn ops in the reference's exact order; exp in double,
// rounded once).

#define LSIDE 2048
#define LMASK 2047
#define LSHIFT 11
#define NCELL (LSIDE * LSIDE)

__global__ __launch_bounds__(256) void spgg_fused(
    const int* __restrict__ tmin,   // type_t_minus
    const int* __restrict__ tt,     // type_t
    const float* __restrict__ Q,    // Q_tensor [N,4]
    const int* __restrict__ ldir,   // learning_direction
    const float* __restrict__ lp,   // learning_probabilities
    float* __restrict__ Qn,         // out: Q_new [N,4]
    float* __restrict__ prof,       // out: profit [N]
    float* __restrict__ t1out)      // out: type_t1 [N]
{
    const int t   = threadIdx.x;
    const int blk = blockIdx.x;
    const int i   = blk >> 1;                       // uniform row per block
    const int j0  = ((blk & 1) << 10) + (t << 2);   // 4-cell group start col
    const int idx0 = (i << LSHIFT) + j0;

    // ---- 1. ldir FIRST (gathers depend on it; in-order vmcnt retirement) --
    const int4   dir4 = *(const int4*)&ldir[idx0];
    const float4 lp4  = *(const float4*)&lp[idx0];
    const int4   A4   = *(const int4*)&tmin[idx0];
    float4 qr0 = ((const float4*)Q)[idx0 + 0];
    float4 qr1 = ((const float4*)Q)[idx0 + 1];
    float4 qr2 = ((const float4*)Q)[idx0 + 2];
    float4 qr3 = ((const float4*)Q)[idx0 + 3];

    // ---- 2. tt window into registers: rows i-3..i+3, scalar row bases ----
    int rowoff[7];
    #pragma unroll
    for (int r = 0; r < 7; ++r) rowoff[r] = ((i + r - 3) & LMASK) << LSHIFT;
    const int cm4 = (j0 - 4) & LMASK;
    const int cm2 = (j0 - 2) & LMASK;
    const int cp4 = (j0 + 4) & LMASK;

    int4 v_m3 = *(const int4*)&tt[rowoff[0] + j0];          // r-3: j0..j0+3
    int2 a_m2 = *(const int2*)&tt[rowoff[1] + cm2];         // r-2: j0-2..j0+4
    int4 b_m2v= *(const int4*)&tt[rowoff[1] + j0];
    int  c_m2 =               tt[rowoff[1] + cp4];
    int2 a_m1 = *(const int2*)&tt[rowoff[2] + cm2];         // r-1: j0-2..j0+5
    int4 b_m1v= *(const int4*)&tt[rowoff[2] + j0];
    int2 c_m1 = *(const int2*)&tt[rowoff[2] + cp4];
    int4 a_0  = *(const int4*)&tt[rowoff[3] + cm4];         // r 0: j0-4..j0+7
    int4 b_0v = *(const int4*)&tt[rowoff[3] + j0];
    int4 c_0v = *(const int4*)&tt[rowoff[3] + cp4];
    int2 a_p1 = *(const int2*)&tt[rowoff[4] + cm2];         // r+1: j0-2..j0+5
    int4 b_p1v= *(const int4*)&tt[rowoff[4] + j0];
    int2 c_p1 = *(const int2*)&tt[rowoff[4] + cp4];
    int2 a_p2 = *(const int2*)&tt[rowoff[5] + cm2];         // r+2: j0-2..j0+4
    int4 b_p2v= *(const int4*)&tt[rowoff[5] + j0];
    int  c_p2 =               tt[rowoff[5] + cp4];
    int4 v_p3 = *(const int4*)&tt[rowoff[6] + j0];          // r+3: j0..j0+3

    // ---- 3. gathers: need only ldir (first load) -> issue now, use last --
    int di[4], dj[4], An[4];
    float4 qn4[4];
    #pragma unroll
    for (int k = 0; k < 4; ++k) {
        int dir = (k == 0) ? dir4.x : (k == 1) ? dir4.y : (k == 2) ? dir4.z : dir4.w;
        // dir: 0=left(j-1) 1=right(j+1) 2=up(i-1) 3=down(i+1)
        di[k] = (dir == 3) - (dir == 2);
        dj[k] = (dir == 1) - (dir == 0);
        int nidx = (((i + di[k]) & LMASK) << LSHIFT) + ((j0 + k + dj[k]) & LMASK);
        qn4[k] = ((const float4*)Q)[nidx];
        An[k]  = tmin[nidx];
    }

    // ---- 4. unpack tt window (all constant indices -> registers) ----
    // Index maps: t_m3[x]=col j0+x; t_m2[x]=j0+x-2; t_m1[x]=j0+x-2;
    //             t_0[x]=j0+x-3;    t_p1[x]=j0+x-2; t_p2[x]=j0+x-2;
    //             t_p3[x]=j0+x.
    int t_m3[4], t_m2[7], t_m1[8], t_0[10], t_p1[8], t_p2[7], t_p3[4];
    t_m3[0]=v_m3.x; t_m3[1]=v_m3.y; t_m3[2]=v_m3.z; t_m3[3]=v_m3.w;
    t_m2[0]=a_m2.x; t_m2[1]=a_m2.y; t_m2[2]=b_m2v.x; t_m2[3]=b_m2v.y;
    t_m2[4]=b_m2v.z; t_m2[5]=b_m2v.w; t_m2[6]=c_m2;
    t_m1[0]=a_m1.x; t_m1[1]=a_m1.y; t_m1[2]=b_m1v.x; t_m1[3]=b_m1v.y;
    t_m1[4]=b_m1v.z; t_m1[5]=b_m1v.w; t_m1[6]=c_m1.x; t_m1[7]=c_m1.y;
    t_0[0]=a_0.y; t_0[1]=a_0.z; t_0[2]=a_0.w;           // j0-3..j0-1
    t_0[3]=b_0v.x; t_0[4]=b_0v.y; t_0[5]=b_0v.z; t_0[6]=b_0v.w;
    t_0[7]=c_0v.x; t_0[8]=c_0v.y; t_0[9]=c_0v.z;        // j0+4..j0+6
    t_p1[0]=a_p1.x; t_p1[1]=a_p1.y; t_p1[2]=b_p1v.x; t_p1[3]=b_p1v.y;
    t_p1[4]=b_p1v.z; t_p1[5]=b_p1v.w; t_p1[6]=c_p1.x; t_p1[7]=c_p1.y;
    t_p2[0]=a_p2.x; t_p2[1]=a_p2.y; t_p2[2]=b_p2v.x; t_p2[3]=b_p2v.y;
    t_p2[4]=b_p2v.z; t_p2[5]=b_p2v.w; t_p2[6]=c_p2;
    t_p3[0]=v_p3.x; t_p3[1]=v_p3.y; t_p3[2]=v_p3.z; t_p3[3]=v_p3.w;

    const float KB        = 0.5554f;  // float32(R / 5.0)
    const float ETA       = 0.8f;
    const float ONE_M_ETA = 0.2f;     // float32(1.0 - 0.8)
    const float GAMMA     = 0.8f;

    // ---- 5. b grid: b = (float)(5-point int sum) * KB (int adds exact) ----
    // conventions: b_m2[c] c=0..3; b_m1[ci] c=ci-1; b_00[ci] c=ci-2;
    //              b_p1[ci] c=ci-1; b_p2[c] c=0..3.
    float b_m2[4], b_m1[6], b_00[8], b_p1[6], b_p2[4];
    #pragma unroll
    for (int c = 0; c < 4; ++c) {
        int cn = t_m2[c+2] + t_m3[c] + t_m1[c+2] + t_m2[c+1] + t_m2[c+3];
        b_m2[c] = __fmul_rn((float)cn, KB);
    }
    #pragma unroll
    for (int ci = 0; ci < 6; ++ci) {   // c = ci-1
        int cn = t_m1[ci+1] + t_m2[ci+1] + t_0[ci+2] + t_m1[ci] + t_m1[ci+2];
        b_m1[ci] = __fmul_rn((float)cn, KB);
    }
    #pragma unroll
    for (int ci = 0; ci < 8; ++ci) {   // c = ci-2
        int cn = t_0[ci+1] + t_m1[ci] + t_p1[ci] + t_0[ci] + t_0[ci+2];
        b_00[ci] = __fmul_rn((float)cn, KB);
    }
    #pragma unroll
    for (int ci = 0; ci < 6; ++ci) {   // c = ci-1
        int cn = t_p1[ci+1] + t_0[ci+2] + t_p2[ci+1] + t_p1[ci] + t_p1[ci+2];
        b_p1[ci] = __fmul_rn((float)cn, KB);
    }
    #pragma unroll
    for (int c = 0; c < 4; ++c) {
        int cn = t_p2[c+2] + t_p1[c+2] + t_p3[c] + t_p2[c+1] + t_p2[c+3];
        b_p2[c] = __fmul_rn((float)cn, KB);
    }

    // profit from 5 b's — reference's exact op order:
    // plus_sum order (c, up, down, left, right); s1 subtracts 1.0 per term.
    auto profit5 = [&](float b_c, float b_u, float b_d, float b_l, float b_r,
                       int coop) -> float {
        float s0 = __fadd_rn(__fadd_rn(__fadd_rn(__fadd_rn(b_c, b_u), b_d), b_l), b_r);
        float s1 = __fadd_rn(__fadd_rn(__fadd_rn(__fadd_rn(
                       __fsub_rn(b_c, 1.0f), __fsub_rn(b_u, 1.0f)),
                       __fsub_rn(b_d, 1.0f)), __fsub_rn(b_l, 1.0f)),
                       __fsub_rn(b_r, 1.0f));
        return coop ? s1 : s0;
    };

    // ---- 6. all candidate profits: row 0 cols j0-1..j0+4, rows +-1 j0..j0+3
    float P0[6], Pm1[4], Pp1[4];
    #pragma unroll
    for (int ci = 0; ci < 6; ++ci)     // c = ci-1
        P0[ci] = profit5(b_00[ci+1], b_m1[ci], b_p1[ci], b_00[ci], b_00[ci+2],
                         t_0[ci+2]);
    #pragma unroll
    for (int c = 0; c < 4; ++c)
        Pm1[c] = profit5(b_m1[c+1], b_m2[c], b_00[c+2], b_m1[c], b_m1[c+2],
                         t_m1[c+2]);
    #pragma unroll
    for (int c = 0; c < 4; ++c)
        Pp1[c] = profit5(b_p1[c+1], b_00[c+2], b_p2[c], b_p1[c], b_p1[c+2],
                         t_p1[c+2]);

    // Q-learning update value — exact reference op order.
    auto upd_of = [&](float profit, float4 q4, int Ai, int Bi) -> float {
        float q0 = (Bi == 0) ? q4.x : q4.z;
        float q1 = (Bi == 0) ? q4.y : q4.w;
        float mx = fmaxf(q0, q1);
        int k = Ai * 2 + Bi;
        float old = (k == 0) ? q4.x : ((k == 1) ? q4.y : ((k == 2) ? q4.z : q4.w));
        float t0 = __fmul_rn(GAMMA, mx);
        float t1 = __fadd_rn(profit, t0);
        float t2 = __fmul_rn(ETA, t1);
        float t3 = __fmul_rn(ONE_M_ETA, old);
        return __fadd_rn(t3, t2);
    };

    // ---- 7. own cells: upd + Q/prof stores (contiguous float4) ----
    int   B[4];
    float updv[4];
    #pragma unroll
    for (int k = 0; k < 4; ++k) {
        B[k] = t_0[k + 3];
        int   Ak = (k == 0) ? A4.x : (k == 1) ? A4.y : (k == 2) ? A4.z : A4.w;
        float4 qk = (k == 0) ? qr0 : (k == 1) ? qr1 : (k == 2) ? qr2 : qr3;
        updv[k] = upd_of(P0[k + 1], qk, Ak, B[k]);
        int kk = Ak * 2 + B[k];
        float4 qo;
        qo.x = (kk == 0) ? updv[k] : qk.x;
        qo.y = (kk == 1) ? updv[k] : qk.y;
        qo.z = (kk == 2) ? updv[k] : qk.z;
        qo.w = (kk == 3) ? updv[k] : qk.w;
        ((float4*)Qn)[idx0 + k] = qo;
    }
    float4 pr4; pr4.x = P0[1]; pr4.y = P0[2]; pr4.z = P0[3]; pr4.w = P0[4];
    *(float4*)&prof[idx0] = pr4;

    // ---- 8. fermi: select neighbor profit/type from registers ----
    float e2[4];
    int   Bn[4];
    #pragma unroll
    for (int k = 0; k < 4; ++k) {
        int dir = (k == 0) ? dir4.x : (k == 1) ? dir4.y : (k == 2) ? dir4.z : dir4.w;
        float Pn = (dir == 0) ? P0[k]       // left  (0, k-1)
                 : (dir == 1) ? P0[k + 2]   // right (0, k+1)
                 : (dir == 2) ? Pm1[k]      // up    (-1, k)
                 :              Pp1[k];     // down  (+1, k)
        Bn[k] = (dir == 0) ? t_0[k + 2]
              : (dir == 1) ? t_0[k + 4]
              : (dir == 2) ? t_m1[k + 2]
              :              t_p1[k + 2];
        float upd_nb = upd_of(Pn, qn4[k], An[k], Bn[k]);
        float e1 = __fsub_rn(updv[k], upd_nb);
        e2[k] = __fmul_rn(e1, 2.0f);        // / K_FERMI(0.5) exactly
    }
    float selv[4];                          // constant-indexed, packed once
    #pragma unroll
    for (int k = 0; k < 4; ++k) {
        float ex = (float)exp((double)e2[k]);   // same as passing rounds
        float W  = __fdiv_rn(1.0f, __fadd_rn(1.0f, ex));
        float pvk = (k == 0) ? lp4.x : (k == 1) ? lp4.y : (k == 2) ? lp4.z : lp4.w;
        int sel = (pvk <= W) ? Bn[k] : B[k];
        selv[k] = (float)sel;
    }
    float4 t14;
    t14.x = selv[0]; t14.y = selv[1]; t14.z = selv[2]; t14.w = selv[3];
    *(float4*)&t1out[idx0] = t14;
}

extern "C" void kernel_launch(void* const* d_in, const int* in_sizes, int n_in,
                              void* d_out, int out_size, void* d_ws, size_t ws_size,
                              hipStream_t stream) {
    const int*   type_t_minus = (const int*)d_in[0];
    const int*   type_t       = (const int*)d_in[1];
    const float* Q_tensor     = (const float*)d_in[2];
    const int*   ldir         = (const int*)d_in[3];
    const float* lprob        = (const float*)d_in[4];

    float* out   = (float*)d_out;
    float* Qn    = out;                       // [N*4]
    float* t1out = out + (size_t)4 * NCELL;   // [N]
    float* prof  = out + (size_t)5 * NCELL;   // [N]

    const int threads = 256;
    const int blocks  = NCELL / (threads * 4);  // 4096 (half-row per block)
    spgg_fused<<<blocks, threads, 0, stream>>>(type_t_minus, type_t, Q_tensor,
                                               ldir, lprob, Qn, prof, t1out);
}

// Round 8
// 249.380 us; speedup vs baseline: 1.0025x; 1.0025x over previous
//
#include <hip/hip_runtime.h>

// SPGG Q-learning step on a 2048x2048 torus — SINGLE fused kernel, v7
// ("regflow" + XCD-contiguous block swizzle).
//
// v6b post-mortem (107.5 us): regflow's compute machine is the cheapest yet
// (VALU issue ~18.5 us, zero LDS, zero bank conflicts) but FETCH exploded
// 75 -> 181 MB (+44 us of HBM traffic): consecutive blocks (adjacent rows
// sharing 6/7 stencil rows) round-robin across 8 XCDs with PRIVATE L2s, so
// each XCD re-fetches ~7/4 of tt and loses Q-gather locality too.
//
// v7 = v6b + bijective XCD swizzle (4096 blocks % 8 == 0):
//     swz = (blk & 7) * 512 + (blk >> 3)
// Round-robin dispatch then hands XCD k the contiguous logical block range
// [512k, 512(k+1)) = one contiguous 256-row band. Per-XCD tt working set
// ~262 rows x 8 KB ~= 2.1 MB < 4 MB private L2 -> 7x row reuse restored,
// Q[nidx]/tmin[nidx] gathers land in the same band. Kernel body unchanged.
//
// Numerics: identical per-cell op sequence as the passing v1-v6b (int-exact
// coop sums; __f*_rn ops in the reference's exact order; exp in double,
// rounded once).

#define LSIDE 2048
#define LMASK 2047
#define LSHIFT 11
#define NCELL (LSIDE * LSIDE)

__global__ __launch_bounds__(256) void spgg_fused(
    const int* __restrict__ tmin,   // type_t_minus
    const int* __restrict__ tt,     // type_t
    const float* __restrict__ Q,    // Q_tensor [N,4]
    const int* __restrict__ ldir,   // learning_direction
    const float* __restrict__ lp,   // learning_probabilities
    float* __restrict__ Qn,         // out: Q_new [N,4]
    float* __restrict__ prof,       // out: profit [N]
    float* __restrict__ t1out)      // out: type_t1 [N]
{
    const int t   = threadIdx.x;
    // XCD-contiguous bijective swizzle: 4096 blocks, 8 XCDs, 512 blocks/XCD.
    // HW round-robins blockIdx.x across XCDs; this remap gives each XCD one
    // contiguous 256-row band -> tt working set ~2.1 MB fits private L2.
    const int blk = ((blockIdx.x & 7) << 9) + (blockIdx.x >> 3);
    const int i   = blk >> 1;                       // uniform row per block
    const int j0  = ((blk & 1) << 10) + (t << 2);   // 4-cell group start col
    const int idx0 = (i << LSHIFT) + j0;

    // ---- 1. ldir FIRST (gathers depend on it; in-order vmcnt retirement) --
    const int4   dir4 = *(const int4*)&ldir[idx0];
    const float4 lp4  = *(const float4*)&lp[idx0];
    const int4   A4   = *(const int4*)&tmin[idx0];
    float4 qr0 = ((const float4*)Q)[idx0 + 0];
    float4 qr1 = ((const float4*)Q)[idx0 + 1];
    float4 qr2 = ((const float4*)Q)[idx0 + 2];
    float4 qr3 = ((const float4*)Q)[idx0 + 3];

    // ---- 2. tt window into registers: rows i-3..i+3, scalar row bases ----
    int rowoff[7];
    #pragma unroll
    for (int r = 0; r < 7; ++r) rowoff[r] = ((i + r - 3) & LMASK) << LSHIFT;
    const int cm4 = (j0 - 4) & LMASK;
    const int cm2 = (j0 - 2) & LMASK;
    const int cp4 = (j0 + 4) & LMASK;

    int4 v_m3 = *(const int4*)&tt[rowoff[0] + j0];          // r-3: j0..j0+3
    int2 a_m2 = *(const int2*)&tt[rowoff[1] + cm2];         // r-2: j0-2..j0+4
    int4 b_m2v= *(const int4*)&tt[rowoff[1] + j0];
    int  c_m2 =               tt[rowoff[1] + cp4];
    int2 a_m1 = *(const int2*)&tt[rowoff[2] + cm2];         // r-1: j0-2..j0+5
    int4 b_m1v= *(const int4*)&tt[rowoff[2] + j0];
    int2 c_m1 = *(const int2*)&tt[rowoff[2] + cp4];
    int4 a_0  = *(const int4*)&tt[rowoff[3] + cm4];         // r 0: j0-4..j0+7
    int4 b_0v = *(const int4*)&tt[rowoff[3] + j0];
    int4 c_0v = *(const int4*)&tt[rowoff[3] + cp4];
    int2 a_p1 = *(const int2*)&tt[rowoff[4] + cm2];         // r+1: j0-2..j0+5
    int4 b_p1v= *(const int4*)&tt[rowoff[4] + j0];
    int2 c_p1 = *(const int2*)&tt[rowoff[4] + cp4];
    int2 a_p2 = *(const int2*)&tt[rowoff[5] + cm2];         // r+2: j0-2..j0+4
    int4 b_p2v= *(const int4*)&tt[rowoff[5] + j0];
    int  c_p2 =               tt[rowoff[5] + cp4];
    int4 v_p3 = *(const int4*)&tt[rowoff[6] + j0];          // r+3: j0..j0+3

    // ---- 3. gathers: need only ldir (first load) -> issue now, use last --
    int di[4], dj[4], An[4];
    float4 qn4[4];
    #pragma unroll
    for (int k = 0; k < 4; ++k) {
        int dir = (k == 0) ? dir4.x : (k == 1) ? dir4.y : (k == 2) ? dir4.z : dir4.w;
        // dir: 0=left(j-1) 1=right(j+1) 2=up(i-1) 3=down(i+1)
        di[k] = (dir == 3) - (dir == 2);
        dj[k] = (dir == 1) - (dir == 0);
        int nidx = (((i + di[k]) & LMASK) << LSHIFT) + ((j0 + k + dj[k]) & LMASK);
        qn4[k] = ((const float4*)Q)[nidx];
        An[k]  = tmin[nidx];
    }

    // ---- 4. unpack tt window (all constant indices -> registers) ----
    // Index maps: t_m3[x]=col j0+x; t_m2[x]=j0+x-2; t_m1[x]=j0+x-2;
    //             t_0[x]=j0+x-3;    t_p1[x]=j0+x-2; t_p2[x]=j0+x-2;
    //             t_p3[x]=j0+x.
    int t_m3[4], t_m2[7], t_m1[8], t_0[10], t_p1[8], t_p2[7], t_p3[4];
    t_m3[0]=v_m3.x; t_m3[1]=v_m3.y; t_m3[2]=v_m3.z; t_m3[3]=v_m3.w;
    t_m2[0]=a_m2.x; t_m2[1]=a_m2.y; t_m2[2]=b_m2v.x; t_m2[3]=b_m2v.y;
    t_m2[4]=b_m2v.z; t_m2[5]=b_m2v.w; t_m2[6]=c_m2;
    t_m1[0]=a_m1.x; t_m1[1]=a_m1.y; t_m1[2]=b_m1v.x; t_m1[3]=b_m1v.y;
    t_m1[4]=b_m1v.z; t_m1[5]=b_m1v.w; t_m1[6]=c_m1.x; t_m1[7]=c_m1.y;
    t_0[0]=a_0.y; t_0[1]=a_0.z; t_0[2]=a_0.w;           // j0-3..j0-1
    t_0[3]=b_0v.x; t_0[4]=b_0v.y; t_0[5]=b_0v.z; t_0[6]=b_0v.w;
    t_0[7]=c_0v.x; t_0[8]=c_0v.y; t_0[9]=c_0v.z;        // j0+4..j0+6
    t_p1[0]=a_p1.x; t_p1[1]=a_p1.y; t_p1[2]=b_p1v.x; t_p1[3]=b_p1v.y;
    t_p1[4]=b_p1v.z; t_p1[5]=b_p1v.w; t_p1[6]=c_p1.x; t_p1[7]=c_p1.y;
    t_p2[0]=a_p2.x; t_p2[1]=a_p2.y; t_p2[2]=b_p2v.x; t_p2[3]=b_p2v.y;
    t_p2[4]=b_p2v.z; t_p2[5]=b_p2v.w; t_p2[6]=c_p2;
    t_p3[0]=v_p3.x; t_p3[1]=v_p3.y; t_p3[2]=v_p3.z; t_p3[3]=v_p3.w;

    const float KB        = 0.5554f;  // float32(R / 5.0)
    const float ETA       = 0.8f;
    const float ONE_M_ETA = 0.2f;     // float32(1.0 - 0.8)
    const float GAMMA     = 0.8f;

    // ---- 5. b grid: b = (float)(5-point int sum) * KB (int adds exact) ----
    // conventions: b_m2[c] c=0..3; b_m1[ci] c=ci-1; b_00[ci] c=ci-2;
    //              b_p1[ci] c=ci-1; b_p2[c] c=0..3.
    float b_m2[4], b_m1[6], b_00[8], b_p1[6], b_p2[4];
    #pragma unroll
    for (int c = 0; c < 4; ++c) {
        int cn = t_m2[c+2] + t_m3[c] + t_m1[c+2] + t_m2[c+1] + t_m2[c+3];
        b_m2[c] = __fmul_rn((float)cn, KB);
    }
    #pragma unroll
    for (int ci = 0; ci < 6; ++ci) {   // c = ci-1
        int cn = t_m1[ci+1] + t_m2[ci+1] + t_0[ci+2] + t_m1[ci] + t_m1[ci+2];
        b_m1[ci] = __fmul_rn((float)cn, KB);
    }
    #pragma unroll
    for (int ci = 0; ci < 8; ++ci) {   // c = ci-2
        int cn = t_0[ci+1] + t_m1[ci] + t_p1[ci] + t_0[ci] + t_0[ci+2];
        b_00[ci] = __fmul_rn((float)cn, KB);
    }
    #pragma unroll
    for (int ci = 0; ci < 6; ++ci) {   // c = ci-1
        int cn = t_p1[ci+1] + t_0[ci+2] + t_p2[ci+1] + t_p1[ci] + t_p1[ci+2];
        b_p1[ci] = __fmul_rn((float)cn, KB);
    }
    #pragma unroll
    for (int c = 0; c < 4; ++c) {
        int cn = t_p2[c+2] + t_p1[c+2] + t_p3[c] + t_p2[c+1] + t_p2[c+3];
        b_p2[c] = __fmul_rn((float)cn, KB);
    }

    // profit from 5 b's — reference's exact op order:
    // plus_sum order (c, up, down, left, right); s1 subtracts 1.0 per term.
    auto profit5 = [&](float b_c, float b_u, float b_d, float b_l, float b_r,
                       int coop) -> float {
        float s0 = __fadd_rn(__fadd_rn(__fadd_rn(__fadd_rn(b_c, b_u), b_d), b_l), b_r);
        float s1 = __fadd_rn(__fadd_rn(__fadd_rn(__fadd_rn(
                       __fsub_rn(b_c, 1.0f), __fsub_rn(b_u, 1.0f)),
                       __fsub_rn(b_d, 1.0f)), __fsub_rn(b_l, 1.0f)),
                       __fsub_rn(b_r, 1.0f));
        return coop ? s1 : s0;
    };

    // ---- 6. all candidate profits: row 0 cols j0-1..j0+4, rows +-1 j0..j0+3
    float P0[6], Pm1[4], Pp1[4];
    #pragma unroll
    for (int ci = 0; ci < 6; ++ci)     // c = ci-1
        P0[ci] = profit5(b_00[ci+1], b_m1[ci], b_p1[ci], b_00[ci], b_00[ci+2],
                         t_0[ci+2]);
    #pragma unroll
    for (int c = 0; c < 4; ++c)
        Pm1[c] = profit5(b_m1[c+1], b_m2[c], b_00[c+2], b_m1[c], b_m1[c+2],
                         t_m1[c+2]);
    #pragma unroll
    for (int c = 0; c < 4; ++c)
        Pp1[c] = profit5(b_p1[c+1], b_00[c+2], b_p2[c], b_p1[c], b_p1[c+2],
                         t_p1[c+2]);

    // Q-learning update value — exact reference op order.
    auto upd_of = [&](float profit, float4 q4, int Ai, int Bi) -> float {
        float q0 = (Bi == 0) ? q4.x : q4.z;
        float q1 = (Bi == 0) ? q4.y : q4.w;
        float mx = fmaxf(q0, q1);
        int k = Ai * 2 + Bi;
        float old = (k == 0) ? q4.x : ((k == 1) ? q4.y : ((k == 2) ? q4.z : q4.w));
        float t0 = __fmul_rn(GAMMA, mx);
        float t1 = __fadd_rn(profit, t0);
        float t2 = __fmul_rn(ETA, t1);
        float t3 = __fmul_rn(ONE_M_ETA, old);
        return __fadd_rn(t3, t2);
    };

    // ---- 7. own cells: upd + Q/prof stores (contiguous float4) ----
    int   B[4];
    float updv[4];
    #pragma unroll
    for (int k = 0; k < 4; ++k) {
        B[k] = t_0[k + 3];
        int   Ak = (k == 0) ? A4.x : (k == 1) ? A4.y : (k == 2) ? A4.z : A4.w;
        float4 qk = (k == 0) ? qr0 : (k == 1) ? qr1 : (k == 2) ? qr2 : qr3;
        updv[k] = upd_of(P0[k + 1], qk, Ak, B[k]);
        int kk = Ak * 2 + B[k];
        float4 qo;
        qo.x = (kk == 0) ? updv[k] : qk.x;
        qo.y = (kk == 1) ? updv[k] : qk.y;
        qo.z = (kk == 2) ? updv[k] : qk.z;
        qo.w = (kk == 3) ? updv[k] : qk.w;
        ((float4*)Qn)[idx0 + k] = qo;
    }
    float4 pr4; pr4.x = P0[1]; pr4.y = P0[2]; pr4.z = P0[3]; pr4.w = P0[4];
    *(float4*)&prof[idx0] = pr4;

    // ---- 8. fermi: select neighbor profit/type from registers ----
    float e2[4];
    int   Bn[4];
    #pragma unroll
    for (int k = 0; k < 4; ++k) {
        int dir = (k == 0) ? dir4.x : (k == 1) ? dir4.y : (k == 2) ? dir4.z : dir4.w;
        float Pn = (dir == 0) ? P0[k]       // left  (0, k-1)
                 : (dir == 1) ? P0[k + 2]   // right (0, k+1)
                 : (dir == 2) ? Pm1[k]      // up    (-1, k)
                 :              Pp1[k];     // down  (+1, k)
        Bn[k] = (dir == 0) ? t_0[k + 2]
              : (dir == 1) ? t_0[k + 4]
              : (dir == 2) ? t_m1[k + 2]
              :              t_p1[k + 2];
        float upd_nb = upd_of(Pn, qn4[k], An[k], Bn[k]);
        float e1 = __fsub_rn(updv[k], upd_nb);
        e2[k] = __fmul_rn(e1, 2.0f);        // / K_FERMI(0.5) exactly
    }
    float selv[4];                          // constant-indexed, packed once
    #pragma unroll
    for (int k = 0; k < 4; ++k) {
        float ex = (float)exp((double)e2[k]);   // same as passing rounds
        float W  = __fdiv_rn(1.0f, __fadd_rn(1.0f, ex));
        float pvk = (k == 0) ? lp4.x : (k == 1) ? lp4.y : (k == 2) ? lp4.z : lp4.w;
        int sel = (pvk <= W) ? Bn[k] : B[k];
        selv[k] = (float)sel;
    }
    float4 t14;
    t14.x = selv[0]; t14.y = selv[1]; t14.z = selv[2]; t14.w = selv[3];
    *(float4*)&t1out[idx0] = t14;
}

extern "C" void kernel_launch(void* const* d_in, const int* in_sizes, int n_in,
                              void* d_out, int out_size, void* d_ws, size_t ws_size,
                              hipStream_t stream) {
    const int*   type_t_minus = (const int*)d_in[0];
    const int*   type_t       = (const int*)d_in[1];
    const float* Q_tensor     = (const float*)d_in[2];
    const int*   ldir         = (const int*)d_in[3];
    const float* lprob        = (const float*)d_in[4];

    float* out   = (float*)d_out;
    float* Qn    = out;                       // [N*4]
    float* t1out = out + (size_t)4 * NCELL;   // [N]
    float* prof  = out + (size_t)5 * NCELL;   // [N]

    const int threads = 256;
    const int blocks  = NCELL / (threads * 4);  // 4096 (half-row per block)
    spgg_fused<<<blocks, threads, 0, stream>>>(type_t_minus, type_t, Q_tensor,
                                               ldir, lprob, Qn, prof, t1out);
}